// Round 3
// baseline (973.574 us; speedup 1.0000x reference)
//
#include <hip/hip_runtime.h>
#include <hip/hip_bf16.h>
#include <math.h>

#define B 64
#define NP 32
#define NS 72
#define NH 4
#define NF 64
#define HD 256
#define CTXD 112
#define NL 4
#define NC 110
#define LN_EPS 1e-6f

// GAT LDS strides
#define SH 68
#define SA 76
// MFMA A-tile LDS stride (bf16 units): 264*2=528B = 33*16B -> 2-way banks on frag reads
#define ALD 264

typedef __hip_bfloat16 bf16;
typedef unsigned short u16;
typedef __attribute__((ext_vector_type(8))) short short8;
typedef __attribute__((ext_vector_type(4))) float floatx4;

__device__ __forceinline__ float ldv(const float* p, int i) { return p[i]; }
__device__ __forceinline__ float ldv(const bf16* p, int i) { return __bfloat162float(p[i]); }
__device__ __forceinline__ void stv(float* p, int i, float v) { p[i] = v; }
__device__ __forceinline__ void stv(bf16* p, int i, float v) { p[i] = __float2bfloat16(v); }
__device__ __forceinline__ u16 f2bfbits(float v) {
  bf16 h = __float2bfloat16(v);
  return *(u16*)&h;
}

// ---------- dtype detector: adj[0,0]==1.0 (self-loop). bf16 1.0 -> halfword 0x3F80.
__global__ void k_detect(const void* adj, int* flag) {
  if (threadIdx.x == 0 && blockIdx.x == 0) {
    *flag = (((const u16*)adj)[0] == 0x3F80u) ? 1 : 0;
  }
}

// ---------- one-time weight transpose: WT[mat][n][k] bf16, mats: Wl*4, Wr*4, opW*4
__global__ void __launch_bounds__(256) k_wt(const void* Wl, const void* Wr, const void* opW,
                                            u16* WT, const int* flag) {
  __shared__ u16 tl[64 * 65];
  int mat = blockIdx.x >> 4, tile = blockIdx.x & 15;
  int k0 = (tile >> 2) * 64, n0 = (tile & 3) * 64;
  const void* src = (mat < 4) ? Wl : (mat < 8) ? Wr : opW;
  int lmat = mat & 3;
  int t = threadIdx.x;
  bool isb = (*flag != 0);
  for (int i = 0; i < 16; ++i) {
    int idx = i * 256 + t; int k = idx >> 6, n = idx & 63;
    size_t off = (size_t)lmat * 65536 + (size_t)(k0 + k) * 256 + n0 + n;
    float v = isb ? __bfloat162float(((const bf16*)src)[off]) : ((const float*)src)[off];
    tl[n * 65 + k] = f2bfbits(v);
  }
  __syncthreads();
  for (int i = 0; i < 16; ++i) {
    int idx = i * 256 + t; int n = idx >> 6, k = idx & 63;
    WT[(size_t)mat * 65536 + (size_t)(n0 + n) * 256 + k0 + k] = tl[n * 65 + k];
  }
}

__device__ __forceinline__ void block_reduce_2(float& a, float& b, float* sred, int t) {
  #pragma unroll
  for (int o = 32; o > 0; o >>= 1) { a += __shfl_down(a, o); b += __shfl_down(b, o); }
  if ((t & 63) == 0) { sred[(t >> 6) * 2] = a; sred[(t >> 6) * 2 + 1] = b; }
  __syncthreads();
  a = sred[0] + sred[2] + sred[4] + sred[6];
  b = sred[1] + sred[3] + sred[5] + sred[7];
}

// ---------- context head: g = relu(LN(ctx @ ctx_W + ctx_b))
template <typename T>
__device__ void ctx_body(const T* cardctx, const T* ctxW, const T* ctxb,
                         const T* lncs, const T* lncb, float* g,
                         float* sred, float* sctx) {
  int b = blockIdx.x, t = threadIdx.x;
  if (t < CTXD) sctx[t] = ldv(cardctx, b * CTXD + t);
  __syncthreads();
  float acc = ldv(ctxb, t);
  for (int k = 0; k < CTXD; ++k) acc += sctx[k] * ldv(ctxW, k * HD + t);
  float a = acc, bb = acc * acc;
  block_reduce_2(a, bb, sred, t);
  float mean = a * (1.f / HD);
  float var = bb * (1.f / HD) - mean * mean;
  float r = rsqrtf(var + LN_EPS);
  float v = (acc - mean) * r * ldv(lncs, t) + ldv(lncb, t);
  g[b * HD + t] = fmaxf(v, 0.f);
}
__global__ void __launch_bounds__(256) k_ctx(const void* cardctx, const void* ctxW, const void* ctxb,
                      const void* lncs, const void* lncb, float* g, const int* flag) {
  __shared__ float sred[8];
  __shared__ float sctx[CTXD];
  if (*flag) ctx_body<bf16>((const bf16*)cardctx, (const bf16*)ctxW, (const bf16*)ctxb,
                            (const bf16*)lncs, (const bf16*)lncb, g, sred, sctx);
  else ctx_body<float>((const float*)cardctx, (const float*)ctxW, (const float*)ctxb,
                       (const float*)lncs, (const float*)lncb, g, sred, sctx);
}

// ---------- input projection
template <typename T>
__device__ void inproj_body(const T* spat, const T* inW, const T* inb, float* x, float* ssp) {
  int blk = blockIdx.x; int b = blk / NS; int s = blk % NS; int t = threadIdx.x;
  if (t < NP) ssp[t] = ldv(spat, (b * NP + t) * NS + s);
  __syncthreads();
  float acc = ldv(inb, t);
  #pragma unroll 8
  for (int p = 0; p < NP; ++p) acc += ssp[p] * ldv(inW, p * HD + t);
  x[blk * HD + t] = acc;
}
__global__ void __launch_bounds__(256) k_inproj(const void* spat, const void* inW, const void* inb,
                         float* x, const int* flag) {
  __shared__ float ssp[NP];
  if (*flag) inproj_body<bf16>((const bf16*)spat, (const bf16*)inW, (const bf16*)inb, x, ssp);
  else inproj_body<float>((const float*)spat, (const float*)inW, (const float*)inb, x, ssp);
}

// ---------- context projection, parallel: grid = B*4, 64 cols x 4 kslices
template <typename T>
__device__ void cproj2_body(const float* g, const T* cpW, const T* cpb, float* c, int l,
                            float* sg, float (*part)[64]) {
  int b = blockIdx.x >> 2, ch = blockIdx.x & 3;
  int t = threadIdx.x;
  sg[t] = g[b * HD + t];
  __syncthreads();
  int col = ch * 64 + (t & 63), s = t >> 6, kb = s * 64;
  const T* W = cpW + (size_t)l * HD * HD;
  float p = 0.f;
  #pragma unroll 8
  for (int k = 0; k < 64; ++k) p += sg[kb + k] * ldv(W, (kb + k) * HD + col);
  part[s][t & 63] = p;
  __syncthreads();
  if (t < 64) {
    int col2 = ch * 64 + t;
    c[b * HD + col2] = part[0][t] + part[1][t] + part[2][t] + part[3][t]
                     + ldv(cpb, l * HD + col2);
  }
}
__global__ void __launch_bounds__(256) k_cproj2(const float* g, const void* cpW, const void* cpb,
                        float* c, int l, const int* flag) {
  __shared__ float sg[HD];
  __shared__ float part[4][64];
  if (*flag) cproj2_body<bf16>(g, (const bf16*)cpW, (const bf16*)cpb, c, l, sg, part);
  else cproj2_body<float>(g, (const float*)cpW, (const float*)cpb, c, l, sg, part);
}

// ---------- h = LN(x)*s + b + c[b]; writes f32 (hf) and bf16 (hb)
template <typename T>
__device__ void lnadd_body(const float* x, const float* c, const T* lnps, const T* lnpb,
                           float* h, bf16* hb, int l, float* sred) {
  int row = blockIdx.x, t = threadIdx.x;
  float v = x[row * HD + t];
  float a = v, bb = v * v;
  block_reduce_2(a, bb, sred, t);
  float mean = a * (1.f / HD);
  float var = bb * (1.f / HD) - mean * mean;
  float r = rsqrtf(var + LN_EPS);
  float o = (v - mean) * r * ldv(lnps, l * HD + t) + ldv(lnpb, l * HD + t)
          + c[(row / NS) * HD + t];
  h[row * HD + t] = o;
  hb[row * HD + t] = __float2bfloat16(o);
}
__global__ void __launch_bounds__(256) k_lnadd(const float* x, const float* c, const void* lnps, const void* lnpb,
                        float* h, bf16* hb, int l, const int* flag) {
  __shared__ float sred[8];
  if (*flag) lnadd_body<bf16>(x, c, (const bf16*)lnps, (const bf16*)lnpb, h, hb, l, sred);
  else lnadd_body<float>(x, c, (const float*)lnps, (const float*)lnpb, h, hb, l, sred);
}

// ---------- MFMA 16-row GEMM core: out[16x256] = A[16x256] @ W, W via WT[n][k] bf16.
// A-frag: lane L holds A[m=L&15][k=(L>>4)*8+j]; B-frag: B[k=(L>>4)*8+j][n=L&15];
// D: row=(L>>4)*4+r, col=L&15  (verified layouts, guide §3)
template <bool ACC>
__device__ void mfma16(const bf16* __restrict__ Ab, const u16* __restrict__ WT,
                       float* __restrict__ out, int M0,
                       const bf16* __restrict__ bias, int boff, u16* A_s) {
  int t = threadIdx.x;
  {
    int row = t >> 4, off = (t & 15) * 16;
    const u16* src = (const u16*)Ab + (M0 + row) * HD + off;
    *(short8*)&A_s[row * ALD + off] = *(const short8*)src;
    *(short8*)&A_s[row * ALD + off + 8] = *(const short8*)(src + 8);
  }
  __syncthreads();
  int w = t >> 6, L = t & 63;
  int n0 = w * 64;
  int q = L >> 4, m16 = L & 15;
  floatx4 acc0 = {0.f, 0.f, 0.f, 0.f};
  floatx4 acc1 = acc0, acc2 = acc0, acc3 = acc0;
  const u16* ap = A_s + m16 * ALD + q * 8;
  const u16* bp = WT + (size_t)(n0 + m16) * HD + q * 8;
  #pragma unroll
  for (int ks = 0; ks < 8; ++ks) {
    short8 a = *(const short8*)(ap + ks * 32);
    short8 b0 = *(const short8*)(bp + ks * 32);
    short8 b1 = *(const short8*)(bp + 16 * HD + ks * 32);
    short8 b2 = *(const short8*)(bp + 32 * HD + ks * 32);
    short8 b3 = *(const short8*)(bp + 48 * HD + ks * 32);
    acc0 = __builtin_amdgcn_mfma_f32_16x16x32_bf16(a, b0, acc0, 0, 0, 0);
    acc1 = __builtin_amdgcn_mfma_f32_16x16x32_bf16(a, b1, acc1, 0, 0, 0);
    acc2 = __builtin_amdgcn_mfma_f32_16x16x32_bf16(a, b2, acc2, 0, 0, 0);
    acc3 = __builtin_amdgcn_mfma_f32_16x16x32_bf16(a, b3, acc3, 0, 0, 0);
  }
  #pragma unroll
  for (int nt = 0; nt < 4; ++nt) {
    floatx4 a4 = (nt == 0) ? acc0 : (nt == 1) ? acc1 : (nt == 2) ? acc2 : acc3;
    int col = n0 + nt * 16 + m16;
    float bv = ACC ? __bfloat162float(bias[boff + col]) : 0.f;
    #pragma unroll
    for (int r = 0; r < 4; ++r) {
      int idx = (M0 + q * 4 + r) * HD + col;
      float v = a4[r] + bv;
      if (ACC) v += out[idx];
      out[idx] = v;
    }
  }
}

// ---------- fp32 vector fallback (flag==0 only): 16 rows, one matrix
__device__ void vec16(const float* A, const float* W, float* out, int M0, bool accf,
                      const float* bias, int boff, float* xs) {
  int t = threadIdx.x;
  for (int i = 0; i < 16; ++i) xs[i * HD + t] = A[(M0 + i) * HD + t];
  __syncthreads();
  float acc[16];
  #pragma unroll
  for (int r = 0; r < 16; ++r) acc[r] = 0.f;
  for (int k = 0; k < HD; ++k) {
    float wv = W[k * HD + t];
    #pragma unroll
    for (int r = 0; r < 16; ++r) acc[r] += xs[r * HD + k] * wv;
  }
  for (int r = 0; r < 16; ++r) {
    float v = acc[r];
    if (accf) v += out[(M0 + r) * HD + t] + bias[boff + t];
    out[(M0 + r) * HD + t] = v;
  }
}

// ---------- gemm_lr: grid 576 = 288 Mtiles x {Wl, Wr}
__global__ void __launch_bounds__(256) k_gemm_lr2(const bf16* hb, const float* hf, const u16* WT,
                         const void* Wl, const void* Wr,
                         float* hl, float* hr, int l, const int* flag) {
  __shared__ u16 A_s[16 * ALD];
  __shared__ float xs[16 * HD];
  bool second = blockIdx.x >= 288;
  int M0 = (second ? blockIdx.x - 288 : blockIdx.x) * 16;
  float* out = second ? hr : hl;
  if (*flag) {
    const u16* wt = WT + (size_t)((second ? 4 : 0) + l) * 65536;
    mfma16<false>(hb, wt, out, M0, nullptr, 0, A_s);
  } else {
    const float* W = (const float*)(second ? Wr : Wl) + (size_t)l * 65536;
    vec16(hf, W, out, M0, false, nullptr, 0, xs);
  }
}

// ---------- gemm_op: grid 288; x += hg @ opW + opb
__global__ void __launch_bounds__(256) k_gemm_op2(const bf16* hgb, const float* hgf, const u16* WT,
                         const void* opW, const void* opb,
                         float* x, int l, const int* flag) {
  __shared__ u16 A_s[16 * ALD];
  __shared__ float xs[16 * HD];
  int M0 = blockIdx.x * 16;
  if (*flag) {
    const u16* wt = WT + (size_t)(8 + l) * 65536;
    mfma16<true>(hgb, wt, x, M0, (const bf16*)opb, l * HD, A_s);
  } else {
    const float* W = (const float*)opW + (size_t)l * 65536;
    vec16(hgf, W, x, M0, true, (const float*)opb, l * HD, xs);
  }
}

// ---------- GATv2: block = (b, head)
template <typename T>
__device__ void gat_body(const float* __restrict__ hl, const float* __restrict__ hr,
                         const T* __restrict__ adj, const T* __restrict__ Wa,
                         float* __restrict__ hg, bf16* __restrict__ hgb, int l,
                         float* hl_s, float* hr_s, float* attnT, float* wa04_s) {
  const int bid = blockIdx.x;
  const int b = bid >> 2, hh = bid & 3;
  const int t = threadIdx.x;
  const int w = t >> 6, L = t & 63;

  const float* hlbase = hl + (size_t)(b * NS) * HD + hh * NF;
  const float* hrbase = hr + (size_t)(b * NS) * HD + hh * NF;

  const float4* hrg1 = (const float4*)(hrbase + L * HD);
  const float4* hrg2 = (const float4*)(hrbase + (64 + (L & 7)) * HD);
  float4 hr1[16], hr2[16];
  #pragma unroll
  for (int q = 0; q < 16; ++q) hr1[q] = hrg1[q];
  #pragma unroll
  for (int q = 0; q < 16; ++q) hr2[q] = hrg2[q];

  if (t < NF) wa04_s[t] = 0.4f * ldv(Wa, l * HD + hh * NF + t);

  const float4* hlg4 = (const float4*)hlbase;
  const float4* hrg4 = (const float4*)hrbase;
  for (int c = t; c < NS * 16; c += 256) {
    int j = c >> 4, q = c & 15;
    *(float4*)&hl_s[j * SH + 4 * q] = hlg4[j * 64 + q];
    *(float4*)&hr_s[j * SH + 4 * q] = hrg4[j * 64 + q];
  }
  __syncthreads();

  float B1 = 0.f, B2 = 0.f;
  #pragma unroll
  for (int q = 0; q < 16; ++q) {
    float4 w4 = *(const float4*)&wa04_s[4 * q];
    B1 = fmaf(w4.x, hr1[q].x, B1); B1 = fmaf(w4.y, hr1[q].y, B1);
    B1 = fmaf(w4.z, hr1[q].z, B1); B1 = fmaf(w4.w, hr1[q].w, B1);
    B2 = fmaf(w4.x, hr2[q].x, B2); B2 = fmaf(w4.y, hr2[q].y, B2);
    B2 = fmaf(w4.z, hr2[q].z, B2); B2 = fmaf(w4.w, hr2[q].w, B2);
  }
  float B15_1 = 1.5f * B1, B15_2 = 1.5f * B2;
  float wa04L = wa04_s[L];

  for (int p = 0; p < 18; ++p) {
    int i = w + 4 * p;
    float av = wa04L * hl_s[i * SH + L];
    #pragma unroll
    for (int o = 32; o > 0; o >>= 1) av += __shfl_xor(av, o);
    float A15 = 1.5f * av;

    float acc1 = 0.f, acc2 = 0.f;
    #pragma unroll
    for (int q = 0; q < 16; ++q) {
      float4 h4 = *(const float4*)&hl_s[i * SH + 4 * q];
      float4 w4 = *(const float4*)&wa04_s[4 * q];
      float e;
      e = h4.x + hr1[q].x; acc1 = fmaf(w4.x, fabsf(e), acc1);
      e = h4.y + hr1[q].y; acc1 = fmaf(w4.y, fabsf(e), acc1);
      e = h4.z + hr1[q].z; acc1 = fmaf(w4.z, fabsf(e), acc1);
      e = h4.w + hr1[q].w; acc1 = fmaf(w4.w, fabsf(e), acc1);
      e = h4.x + hr2[q].x; acc2 = fmaf(w4.x, fabsf(e), acc2);
      e = h4.y + hr2[q].y; acc2 = fmaf(w4.y, fabsf(e), acc2);
      e = h4.z + hr2[q].z; acc2 = fmaf(w4.z, fabsf(e), acc2);
      e = h4.w + hr2[q].w; acc2 = fmaf(w4.w, fabsf(e), acc2);
    }
    float s1 = A15 + B15_1 + acc1;
    float s2 = A15 + B15_2 + acc2;
    float a1 = ldv(adj, i * NS + L);
    s1 = (a1 > 0.f) ? s1 : -1e30f;
    if (L < 8) {
      float a2 = ldv(adj, i * NS + 64 + L);
      s2 = (a2 > 0.f) ? s2 : -1e30f;
    } else {
      s2 = -1e30f;
    }
    float m = fmaxf(s1, s2);
    #pragma unroll
    for (int o = 32; o > 0; o >>= 1) m = fmaxf(m, __shfl_xor(m, o));
    float e1 = __expf(s1 - m);
    float e2 = __expf(s2 - m);
    float se = e1 + e2;
    #pragma unroll
    for (int o = 32; o > 0; o >>= 1) se += __shfl_xor(se, o);
    float inv = 1.f / se;
    attnT[L * SA + i] = e1 * inv;
    if (L < 8) attnT[(64 + L) * SA + i] = e2 * inv;
  }
  __syncthreads();

  for (int p = 0; p < 5; ++p) {
    int g = w + 4 * p;
    if (g >= 18) break;
    int i0 = 4 * g;
    float a0 = 0.f, a1 = 0.f, a2 = 0.f, a3 = 0.f;
    #pragma unroll 4
    for (int j = 0; j < NS; ++j) {
      float4 at = *(const float4*)&attnT[j * SA + i0];
      float hv = hr_s[j * SH + L];
      a0 = fmaf(at.x, hv, a0); a1 = fmaf(at.y, hv, a1);
      a2 = fmaf(at.z, hv, a2); a3 = fmaf(at.w, hv, a3);
    }
    size_t o = (size_t)(b * NS + i0) * HD + hh * NF + L;
    hg[o] = a0; hg[o + HD] = a1; hg[o + 2 * HD] = a2; hg[o + 3 * HD] = a3;
    hgb[o] = __float2bfloat16(a0); hgb[o + HD] = __float2bfloat16(a1);
    hgb[o + 2 * HD] = __float2bfloat16(a2); hgb[o + 3 * HD] = __float2bfloat16(a3);
  }
}
__global__ void __launch_bounds__(256, 1) k_gat(const float* hl, const float* hr, const void* adj, const void* Wa,
                      float* hg, bf16* hgb, int l, const int* flag) {
  __shared__ float hl_s[NS * SH];
  __shared__ float hr_s[NS * SH];
  __shared__ float attnT[NS * SA];
  __shared__ float wa04_s[NF];
  if (*flag) gat_body<bf16>(hl, hr, (const bf16*)adj, (const bf16*)Wa, hg, hgb, l, hl_s, hr_s, attnT, wa04_s);
  else gat_body<float>(hl, hr, (const float*)adj, (const float*)Wa, hg, hgb, l, hl_s, hr_s, attnT, wa04_s);
}

// ---------- ge = mean over nodes
__global__ void __launch_bounds__(256) k_ge(const float* x, float* ge) {
  int b = blockIdx.x, t = threadIdx.x;
  float a = 0.f;
  for (int s = 0; s < NS; ++s) a += x[(b * NS + s) * HD + t];
  ge[b * HD + t] = a * (1.f / NS);
}

// ---------- heads, chunked: grid = B*7, 64 cols x 4 kslices per block
template <typename T>
__device__ void heads2_body(const float* ge,
                            const T* cardW, const T* cardb, const T* atW, const T* atb,
                            const T* srcW, const T* srcb, const T* tgtW, const T* tgtb,
                            const T* v1W, const T* v1b, T* out, float* r1,
                            float* sge, float (*part)[64]) {
  int b = blockIdx.x / 7, ch = blockIdx.x % 7;
  int t = threadIdx.x;
  sge[t] = ge[b * HD + t];
  __syncthreads();
  int c = ch * 64 + (t & 63);
  int s = t >> 6;
  const T* W = nullptr; int ld = 0, cc = 0;
  if (c < 110)      { W = cardW; ld = 110; cc = c; }
  else if (c < 113) { W = atW;   ld = 3;   cc = c - 110; }
  else if (c < 185) { W = srcW;  ld = 72;  cc = c - 113; }
  else if (c < 257) { W = tgtW;  ld = 72;  cc = c - 185; }
  else if (c < 385) { W = v1W;   ld = 128; cc = c - 257; }
  float p = 0.f;
  if (W) {
    int kb = s * 64;
    #pragma unroll 8
    for (int k = 0; k < 64; ++k) p += sge[kb + k] * ldv(W, (kb + k) * ld + cc);
  }
  part[s][t & 63] = p;
  __syncthreads();
  if (t < 64) {
    int c2 = ch * 64 + t;
    float v = part[0][t] + part[1][t] + part[2][t] + part[3][t];
    if (c2 < 110)      stv(out, b * 110 + c2, v + ldv(cardb, c2));
    else if (c2 < 113) stv(out, 7040 + b * 3 + (c2 - 110), v + ldv(atb, c2 - 110));
    else if (c2 < 185) stv(out, 7232 + b * 72 + (c2 - 113), v + ldv(srcb, c2 - 113));
    else if (c2 < 257) stv(out, 11840 + b * 72 + (c2 - 185), v + ldv(tgtb, c2 - 185));
    else if (c2 < 385) r1[b * 128 + (c2 - 257)] = fmaxf(v + ldv(v1b, c2 - 257), 0.f);
  }
}
__global__ void __launch_bounds__(256) k_heads2(const float* ge,
                        const void* cardW, const void* cardb, const void* atW, const void* atb,
                        const void* srcW, const void* srcb, const void* tgtW, const void* tgtb,
                        const void* v1W, const void* v1b, void* out, float* r1, const int* flag) {
  __shared__ float sge[HD];
  __shared__ float part[4][64];
  if (*flag) heads2_body<bf16>(ge, (const bf16*)cardW, (const bf16*)cardb, (const bf16*)atW,
                               (const bf16*)atb, (const bf16*)srcW, (const bf16*)srcb,
                               (const bf16*)tgtW, (const bf16*)tgtb, (const bf16*)v1W,
                               (const bf16*)v1b, (bf16*)out, r1, sge, part);
  else heads2_body<float>(ge, (const float*)cardW, (const float*)cardb, (const float*)atW,
                          (const float*)atb, (const float*)srcW, (const float*)srcb,
                          (const float*)tgtW, (const float*)tgtb, (const float*)v1W,
                          (const float*)v1b, (float*)out, r1, sge, part);
}

// ---------- value head
template <typename T>
__device__ void value_body(const float* r1, const T* v2W, const T* v2b, T* out) {
  int b = blockIdx.x, t = threadIdx.x;
  float v = r1[b * 128 + t] * ldv(v2W, t) + r1[b * 128 + 64 + t] * ldv(v2W, 64 + t);
  #pragma unroll
  for (int o = 32; o > 0; o >>= 1) v += __shfl_xor(v, o);
  if (t == 0) stv(out, 16448 + b, tanhf(v + ldv(v2b, 0)));
}
__global__ void __launch_bounds__(64) k_value(const float* r1, const void* v2W, const void* v2b,
                       void* out, const int* flag) {
  if (*flag) value_body<bf16>(r1, (const bf16*)v2W, (const bf16*)v2b, (bf16*)out);
  else value_body<float>(r1, (const float*)v2W, (const float*)v2b, (float*)out);
}

extern "C" void kernel_launch(void* const* d_in, const int* in_sizes, int n_in,
                              void* d_out, int out_size, void* d_ws, size_t ws_size,
                              hipStream_t stream) {
  const void* spatial = d_in[0];
  const void* cardctx = d_in[1];
  const void* adj = d_in[2];
  const void* ctxW = d_in[3]; const void* ctxb = d_in[4];
  const void* lncs = d_in[5]; const void* lncb = d_in[6];
  const void* inW = d_in[7];  const void* inb = d_in[8];
  const void* lnps = d_in[9]; const void* lnpb = d_in[10];
  const void* cpW = d_in[11]; const void* cpb = d_in[12];
  const void* Wl = d_in[13];  const void* Wr = d_in[14]; const void* Wa = d_in[15];
  const void* opW = d_in[16]; const void* opb = d_in[17];
  const void* cardW = d_in[18]; const void* cardb = d_in[19];
  const void* atW = d_in[20];   const void* atb = d_in[21];
  const void* srcW = d_in[22];  const void* srcb = d_in[23];
  const void* tgtW = d_in[24];  const void* tgtb = d_in[25];
  const void* v1W = d_in[26];   const void* v1b = d_in[27];
  const void* v2W = d_in[28];   const void* v2b = d_in[29];

  int* flag = (int*)d_ws;
  float* base = (float*)((char*)d_ws + 256);
  float* g   = base;                  // B*HD
  float* c   = g + B * HD;            // B*HD
  float* x   = c + B * HD;            // B*NS*HD
  float* hf  = x + B * NS * HD;       // B*NS*HD (h f32, reused as hg f32)
  float* hl  = hf + B * NS * HD;      // B*NS*HD
  float* hr  = hl + B * NS * HD;      // B*NS*HD
  float* ge  = hr + B * NS * HD;      // B*HD
  float* r1  = ge + B * HD;           // B*128
  u16* breg  = (u16*)(r1 + B * 128);
  bf16* hb   = (bf16*)breg;           // B*NS*HD bf16
  bf16* hgb  = hb + B * NS * HD;      // B*NS*HD bf16
  u16* WT    = (u16*)(hgb + B * NS * HD); // 12*65536 bf16

  k_detect<<<1, 64, 0, stream>>>(adj, flag);
  k_wt<<<192, 256, 0, stream>>>(Wl, Wr, opW, WT, flag);
  k_ctx<<<B, HD, 0, stream>>>(cardctx, ctxW, ctxb, lncs, lncb, g, flag);
  k_inproj<<<B * NS, HD, 0, stream>>>(spatial, inW, inb, x, flag);
  for (int l = 0; l < NL; ++l) {
    k_cproj2<<<B * 4, HD, 0, stream>>>(g, cpW, cpb, c, l, flag);
    k_lnadd<<<B * NS, HD, 0, stream>>>(x, c, lnps, lnpb, hf, hb, l, flag);
    k_gemm_lr2<<<576, 256, 0, stream>>>(hb, hf, WT, Wl, Wr, hl, hr, l, flag);
    k_gat<<<B * NH, 256, 0, stream>>>(hl, hr, adj, Wa, hf, hgb, l, flag);
    k_gemm_op2<<<288, 256, 0, stream>>>(hgb, hf, WT, opW, opb, x, l, flag);
  }
  k_ge<<<B, HD, 0, stream>>>(x, ge);
  k_heads2<<<B * 7, 256, 0, stream>>>(ge, cardW, cardb, atW, atb, srcW, srcb, tgtW, tgtb,
                                      v1W, v1b, d_out, r1, flag);
  k_value<<<B, 64, 0, stream>>>(r1, v2W, v2b, d_out, flag);
}

// Round 4
// 798.167 us; speedup vs baseline: 1.2198x; 1.2198x over previous
//
#include <hip/hip_runtime.h>
#include <hip/hip_bf16.h>
#include <math.h>

#define B 64
#define NP 32
#define NS 72
#define NH 4
#define NF 64
#define HD 256
#define CTXD 112
#define NL 4
#define NC 110
#define LN_EPS 1e-6f

// GAT LDS strides
#define SH 68
#define SA 76
// MFMA A-tile LDS stride (bf16 units)
#define ALD 264

typedef __hip_bfloat16 bf16;
typedef unsigned short u16;
typedef __attribute__((ext_vector_type(8))) short short8;
typedef __attribute__((ext_vector_type(4))) float floatx4;

__device__ __forceinline__ float ldv(const float* p, int i) { return p[i]; }
__device__ __forceinline__ float ldv(const bf16* p, int i) { return __bfloat162float(p[i]); }
__device__ __forceinline__ void stv(float* p, int i, float v) { p[i] = v; }
__device__ __forceinline__ void stv(bf16* p, int i, float v) { p[i] = __float2bfloat16(v); }
__device__ __forceinline__ u16 f2bfbits(float v) {
  bf16 h = __float2bfloat16(v);
  return *(u16*)&h;
}

// ---------- dtype detector: adj[0,0]==1.0 (self-loop). bf16 1.0 -> halfword 0x3F80.
__global__ void k_detect(const void* adj, int* flag) {
  if (threadIdx.x == 0 && blockIdx.x == 0) {
    *flag = (((const u16*)adj)[0] == 0x3F80u) ? 1 : 0;
  }
}

// ---------- one-time weight transpose: WT[mat][n][k] bf16, mats: Wl*4, Wr*4, opW*4
__global__ void __launch_bounds__(256) k_wt(const void* Wl, const void* Wr, const void* opW,
                                            u16* WT, const int* flag) {
  __shared__ u16 tl[64 * 65];
  int mat = blockIdx.x >> 4, tile = blockIdx.x & 15;
  int k0 = (tile >> 2) * 64, n0 = (tile & 3) * 64;
  const void* src = (mat < 4) ? Wl : (mat < 8) ? Wr : opW;
  int lmat = mat & 3;
  int t = threadIdx.x;
  bool isb = (*flag != 0);
  for (int i = 0; i < 16; ++i) {
    int idx = i * 256 + t; int k = idx >> 6, n = idx & 63;
    size_t off = (size_t)lmat * 65536 + (size_t)(k0 + k) * 256 + n0 + n;
    float v = isb ? __bfloat162float(((const bf16*)src)[off]) : ((const float*)src)[off];
    tl[n * 65 + k] = f2bfbits(v);
  }
  __syncthreads();
  for (int i = 0; i < 16; ++i) {
    int idx = i * 256 + t; int n = idx >> 6, k = idx & 63;
    WT[(size_t)mat * 65536 + (size_t)(n0 + n) * 256 + k0 + k] = tl[n * 65 + k];
  }
}

__device__ __forceinline__ void block_reduce_2(float& a, float& b, float* sred, int t) {
  #pragma unroll
  for (int o = 32; o > 0; o >>= 1) { a += __shfl_down(a, o); b += __shfl_down(b, o); }
  if ((t & 63) == 0) { sred[(t >> 6) * 2] = a; sred[(t >> 6) * 2 + 1] = b; }
  __syncthreads();
  a = sred[0] + sred[2] + sred[4] + sred[6];
  b = sred[1] + sred[3] + sred[5] + sred[7];
}

// ---------- context head: g = relu(LN(ctx @ ctx_W + ctx_b))
template <typename T>
__device__ void ctx_body(const T* cardctx, const T* ctxW, const T* ctxb,
                         const T* lncs, const T* lncb, float* g,
                         float* sred, float* sctx) {
  int b = blockIdx.x, t = threadIdx.x;
  if (t < CTXD) sctx[t] = ldv(cardctx, b * CTXD + t);
  __syncthreads();
  float acc = ldv(ctxb, t);
  for (int k = 0; k < CTXD; ++k) acc += sctx[k] * ldv(ctxW, k * HD + t);
  float a = acc, bb = acc * acc;
  block_reduce_2(a, bb, sred, t);
  float mean = a * (1.f / HD);
  float var = bb * (1.f / HD) - mean * mean;
  float r = rsqrtf(var + LN_EPS);
  float v = (acc - mean) * r * ldv(lncs, t) + ldv(lncb, t);
  g[b * HD + t] = fmaxf(v, 0.f);
}
__global__ void __launch_bounds__(256) k_ctx(const void* cardctx, const void* ctxW, const void* ctxb,
                      const void* lncs, const void* lncb, float* g, const int* flag) {
  __shared__ float sred[8];
  __shared__ float sctx[CTXD];
  if (*flag) ctx_body<bf16>((const bf16*)cardctx, (const bf16*)ctxW, (const bf16*)ctxb,
                            (const bf16*)lncs, (const bf16*)lncb, g, sred, sctx);
  else ctx_body<float>((const float*)cardctx, (const float*)ctxW, (const float*)ctxb,
                       (const float*)lncs, (const float*)lncb, g, sred, sctx);
}

// ---------- input projection
template <typename T>
__device__ void inproj_body(const T* spat, const T* inW, const T* inb, float* x, float* ssp) {
  int blk = blockIdx.x; int b = blk / NS; int s = blk % NS; int t = threadIdx.x;
  if (t < NP) ssp[t] = ldv(spat, (b * NP + t) * NS + s);
  __syncthreads();
  float acc = ldv(inb, t);
  #pragma unroll 8
  for (int p = 0; p < NP; ++p) acc += ssp[p] * ldv(inW, p * HD + t);
  x[blk * HD + t] = acc;
}
__global__ void __launch_bounds__(256) k_inproj(const void* spat, const void* inW, const void* inb,
                         float* x, const int* flag) {
  __shared__ float ssp[NP];
  if (*flag) inproj_body<bf16>((const bf16*)spat, (const bf16*)inW, (const bf16*)inb, x, ssp);
  else inproj_body<float>((const float*)spat, (const float*)inW, (const float*)inb, x, ssp);
}

// ---------- context projections for ALL layers upfront: grid = NL*B*4
template <typename T>
__device__ void cproja_body(const float* g, const T* cpW, const T* cpb, float* c,
                            float* sg, float (*part)[64]) {
  int bid = blockIdx.x;
  int l = bid >> 8;          // 256 blocks per layer
  int rest = bid & 255;
  int b = rest >> 2, ch = rest & 3;
  int t = threadIdx.x;
  sg[t] = g[b * HD + t];
  __syncthreads();
  int col = ch * 64 + (t & 63), s = t >> 6, kb = s * 64;
  const T* W = cpW + (size_t)l * HD * HD;
  float p = 0.f;
  #pragma unroll 8
  for (int k = 0; k < 64; ++k) p += sg[kb + k] * ldv(W, (kb + k) * HD + col);
  part[s][t & 63] = p;
  __syncthreads();
  if (t < 64) {
    int col2 = ch * 64 + t;
    c[(size_t)l * B * HD + b * HD + col2] =
        part[0][t] + part[1][t] + part[2][t] + part[3][t] + ldv(cpb, l * HD + col2);
  }
}
__global__ void __launch_bounds__(256) k_cproja(const float* g, const void* cpW, const void* cpb,
                        float* c, const int* flag) {
  __shared__ float sg[HD];
  __shared__ float part[4][64];
  if (*flag) cproja_body<bf16>(g, (const bf16*)cpW, (const bf16*)cpb, c, sg, part);
  else cproja_body<float>(g, (const float*)cpW, (const float*)cpb, c, sg, part);
}

// ---------- h = LN(x)*s + b + c[b]; writes f32 (hf, for fallback) and bf16 (hb)
template <typename T>
__device__ void lnadd_body(const float* x, const float* c, const T* lnps, const T* lnpb,
                           float* h, bf16* hb, int l, float* sred) {
  int row = blockIdx.x, t = threadIdx.x;
  float v = x[row * HD + t];
  float a = v, bb = v * v;
  block_reduce_2(a, bb, sred, t);
  float mean = a * (1.f / HD);
  float var = bb * (1.f / HD) - mean * mean;
  float r = rsqrtf(var + LN_EPS);
  float o = (v - mean) * r * ldv(lnps, l * HD + t) + ldv(lnpb, l * HD + t)
          + c[(row / NS) * HD + t];
  h[row * HD + t] = o;
  hb[row * HD + t] = __float2bfloat16(o);
}
__global__ void __launch_bounds__(256) k_lnadd(const float* x, const float* c, const void* lnps, const void* lnpb,
                        float* h, bf16* hb, int l, const int* flag) {
  __shared__ float sred[8];
  if (*flag) lnadd_body<bf16>(x, c, (const bf16*)lnps, (const bf16*)lnpb, h, hb, l, sred);
  else lnadd_body<float>(x, c, (const float*)lnps, (const float*)lnpb, h, hb, l, sred);
}

// ---------- MFMA core: B-frags resident in registers (32 x short8 = 128 VGPR),
// M-tiles stream through LDS. Wave w owns n-strip [w*64, w*64+64).
// A-frag: lane L holds A[m=L&15][k=(L>>4)*8+j]; B-frag: B[k=(L>>4)*8+j][n=L&15];
// D: row=(L>>4)*4+r, col=L&15  (verified layouts, R3 passed with these)
template <int MT, bool ACC>
__device__ void mfma_core(const bf16* __restrict__ Ab, const u16* __restrict__ WT,
                          float* __restrict__ out, int M0,
                          const bf16* __restrict__ bias, int boff, u16* A_s) {
  int t = threadIdx.x;
  int w = t >> 6, L = t & 63;
  int q = L >> 4, m16 = L & 15;
  int n0 = w * 64;

  // load all B fragments once
  short8 bfrag[8][4];
  const u16* bp = WT + (size_t)(n0 + m16) * HD + q * 8;
  #pragma unroll
  for (int ks = 0; ks < 8; ++ks)
    #pragma unroll
    for (int nt = 0; nt < 4; ++nt)
      bfrag[ks][nt] = *(const short8*)(bp + (size_t)nt * 16 * HD + ks * 32);

  // stage MT*16 A-rows to LDS (coalesced 32B per lane per row-group)
  const u16* ag = (const u16*)Ab + (size_t)M0 * HD;
  #pragma unroll
  for (int rg = 0; rg < MT; ++rg) {
    int row = rg * 16 + (t >> 4), off = (t & 15) * 16;
    *(short8*)&A_s[row * ALD + off] = *(const short8*)(ag + (size_t)row * HD + off);
    *(short8*)&A_s[row * ALD + off + 8] = *(const short8*)(ag + (size_t)row * HD + off + 8);
  }
  __syncthreads();

  #pragma unroll
  for (int mt = 0; mt < MT; ++mt) {
    floatx4 acc0 = {0.f, 0.f, 0.f, 0.f};
    floatx4 acc1 = acc0, acc2 = acc0, acc3 = acc0;
    const u16* ap = A_s + (mt * 16 + m16) * ALD + q * 8;
    #pragma unroll
    for (int ks = 0; ks < 8; ++ks) {
      short8 a = *(const short8*)(ap + ks * 32);
      acc0 = __builtin_amdgcn_mfma_f32_16x16x32_bf16(a, bfrag[ks][0], acc0, 0, 0, 0);
      acc1 = __builtin_amdgcn_mfma_f32_16x16x32_bf16(a, bfrag[ks][1], acc1, 0, 0, 0);
      acc2 = __builtin_amdgcn_mfma_f32_16x16x32_bf16(a, bfrag[ks][2], acc2, 0, 0, 0);
      acc3 = __builtin_amdgcn_mfma_f32_16x16x32_bf16(a, bfrag[ks][3], acc3, 0, 0, 0);
    }
    #pragma unroll
    for (int nt = 0; nt < 4; ++nt) {
      floatx4 a4 = (nt == 0) ? acc0 : (nt == 1) ? acc1 : (nt == 2) ? acc2 : acc3;
      int col = n0 + nt * 16 + m16;
      float bv = ACC ? __bfloat162float(bias[boff + col]) : 0.f;
      #pragma unroll
      for (int r = 0; r < 4; ++r) {
        size_t idx = (size_t)(M0 + mt * 16 + q * 4 + r) * HD + col;
        float v = a4[r] + bv;
        if (ACC) v += out[idx];
        out[idx] = v;
      }
    }
  }
}

// ---------- fp32 vector fallback (flag==0 only): 16 rows, one matrix
__device__ void vec16(const float* A, const float* W, float* out, int M0, bool accf,
                      const float* bias, int boff, float* xs) {
  int t = threadIdx.x;
  for (int i = 0; i < 16; ++i) xs[i * HD + t] = A[(size_t)(M0 + i) * HD + t];
  __syncthreads();
  float acc[16];
  #pragma unroll
  for (int r = 0; r < 16; ++r) acc[r] = 0.f;
  for (int k = 0; k < HD; ++k) {
    float wv = W[k * HD + t];
    #pragma unroll
    for (int r = 0; r < 16; ++r) acc[r] += xs[r * HD + k] * wv;
  }
  for (int r = 0; r < 16; ++r) {
    float v = acc[r];
    if (accf) v += out[(size_t)(M0 + r) * HD + t] + bias[boff + t];
    out[(size_t)(M0 + r) * HD + t] = v;
  }
}

// ---------- gemm_lr: grid 144 = 72 Mblocks(64 rows) x {Wl, Wr}
__global__ void __launch_bounds__(256) k_gemm_lr3(const bf16* hb, const float* hf, const u16* WT,
                         const void* Wl, const void* Wr,
                         float* hl, float* hr, int l, const int* flag) {
  __shared__ u16 A_s[64 * ALD];
  __shared__ float xs[16 * HD];
  bool second = blockIdx.x >= 72;
  int M0 = (second ? blockIdx.x - 72 : blockIdx.x) * 64;
  float* out = second ? hr : hl;
  if (*flag) {
    const u16* wt = WT + (size_t)((second ? 4 : 0) + l) * 65536;
    mfma_core<4, false>(hb, wt, out, M0, nullptr, 0, A_s);
  } else {
    const float* W = (const float*)(second ? Wr : Wl) + (size_t)l * 65536;
    for (int mt = 0; mt < 4; ++mt) {
      vec16(hf, W, out, M0 + mt * 16, false, nullptr, 0, xs);
      __syncthreads();
    }
  }
}

// ---------- gemm_op: grid 144 (32 rows each); x += hg @ opW + opb
__global__ void __launch_bounds__(256) k_gemm_op3(const bf16* hgb, const float* hgf, const u16* WT,
                         const void* opW, const void* opb,
                         float* x, int l, const int* flag) {
  __shared__ u16 A_s[64 * ALD];
  __shared__ float xs[16 * HD];
  int M0 = blockIdx.x * 32;
  if (*flag) {
    const u16* wt = WT + (size_t)(8 + l) * 65536;
    mfma_core<2, true>(hgb, wt, x, M0, (const bf16*)opb, l * HD, A_s);
  } else {
    const float* W = (const float*)opW + (size_t)l * 65536;
    for (int mt = 0; mt < 2; ++mt) {
      vec16(hgf, W, x, M0 + mt * 16, true, (const float*)opb, l * HD, xs);
      __syncthreads();
    }
  }
}

// ---------- GATv2: block = (b, head)
template <typename T>
__device__ void gat_body(const float* __restrict__ hl, const float* __restrict__ hr,
                         const T* __restrict__ adj, const T* __restrict__ Wa,
                         float* __restrict__ hg, bf16* __restrict__ hgb, int l,
                         float* hl_s, float* hr_s, float* attnT, float* wa04_s) {
  const int bid = blockIdx.x;
  const int b = bid >> 2, hh = bid & 3;
  const int t = threadIdx.x;
  const int w = t >> 6, L = t & 63;

  const float* hlbase = hl + (size_t)(b * NS) * HD + hh * NF;
  const float* hrbase = hr + (size_t)(b * NS) * HD + hh * NF;

  const float4* hrg1 = (const float4*)(hrbase + L * HD);
  const float4* hrg2 = (const float4*)(hrbase + (64 + (L & 7)) * HD);
  float4 hr1[16], hr2[16];
  #pragma unroll
  for (int q = 0; q < 16; ++q) hr1[q] = hrg1[q];
  #pragma unroll
  for (int q = 0; q < 16; ++q) hr2[q] = hrg2[q];

  if (t < NF) wa04_s[t] = 0.4f * ldv(Wa, l * HD + hh * NF + t);

  const float4* hlg4 = (const float4*)hlbase;
  const float4* hrg4 = (const float4*)hrbase;
  for (int c = t; c < NS * 16; c += 256) {
    int j = c >> 4, q = c & 15;
    *(float4*)&hl_s[j * SH + 4 * q] = hlg4[j * 64 + q];
    *(float4*)&hr_s[j * SH + 4 * q] = hrg4[j * 64 + q];
  }
  __syncthreads();

  float B1 = 0.f, B2 = 0.f;
  #pragma unroll
  for (int q = 0; q < 16; ++q) {
    float4 w4 = *(const float4*)&wa04_s[4 * q];
    B1 = fmaf(w4.x, hr1[q].x, B1); B1 = fmaf(w4.y, hr1[q].y, B1);
    B1 = fmaf(w4.z, hr1[q].z, B1); B1 = fmaf(w4.w, hr1[q].w, B1);
    B2 = fmaf(w4.x, hr2[q].x, B2); B2 = fmaf(w4.y, hr2[q].y, B2);
    B2 = fmaf(w4.z, hr2[q].z, B2); B2 = fmaf(w4.w, hr2[q].w, B2);
  }
  float B15_1 = 1.5f * B1, B15_2 = 1.5f * B2;
  float wa04L = wa04_s[L];

  for (int p = 0; p < 18; ++p) {
    int i = w + 4 * p;
    float av = wa04L * hl_s[i * SH + L];
    #pragma unroll
    for (int o = 32; o > 0; o >>= 1) av += __shfl_xor(av, o);
    float A15 = 1.5f * av;

    float acc1 = 0.f, acc2 = 0.f;
    #pragma unroll
    for (int q = 0; q < 16; ++q) {
      float4 h4 = *(const float4*)&hl_s[i * SH + 4 * q];
      float4 w4 = *(const float4*)&wa04_s[4 * q];
      float e;
      e = h4.x + hr1[q].x; acc1 = fmaf(w4.x, fabsf(e), acc1);
      e = h4.y + hr1[q].y; acc1 = fmaf(w4.y, fabsf(e), acc1);
      e = h4.z + hr1[q].z; acc1 = fmaf(w4.z, fabsf(e), acc1);
      e = h4.w + hr1[q].w; acc1 = fmaf(w4.w, fabsf(e), acc1);
      e = h4.x + hr2[q].x; acc2 = fmaf(w4.x, fabsf(e), acc2);
      e = h4.y + hr2[q].y; acc2 = fmaf(w4.y, fabsf(e), acc2);
      e = h4.z + hr2[q].z; acc2 = fmaf(w4.z, fabsf(e), acc2);
      e = h4.w + hr2[q].w; acc2 = fmaf(w4.w, fabsf(e), acc2);
    }
    float s1 = A15 + B15_1 + acc1;
    float s2 = A15 + B15_2 + acc2;
    float a1 = ldv(adj, i * NS + L);
    s1 = (a1 > 0.f) ? s1 : -1e30f;
    if (L < 8) {
      float a2 = ldv(adj, i * NS + 64 + L);
      s2 = (a2 > 0.f) ? s2 : -1e30f;
    } else {
      s2 = -1e30f;
    }
    float m = fmaxf(s1, s2);
    #pragma unroll
    for (int o = 32; o > 0; o >>= 1) m = fmaxf(m, __shfl_xor(m, o));
    float e1 = __expf(s1 - m);
    float e2 = __expf(s2 - m);
    float se = e1 + e2;
    #pragma unroll
    for (int o = 32; o > 0; o >>= 1) se += __shfl_xor(se, o);
    float inv = 1.f / se;
    attnT[L * SA + i] = e1 * inv;
    if (L < 8) attnT[(64 + L) * SA + i] = e2 * inv;
  }
  __syncthreads();

  for (int p = 0; p < 5; ++p) {
    int g = w + 4 * p;
    if (g >= 18) break;
    int i0 = 4 * g;
    float a0 = 0.f, a1 = 0.f, a2 = 0.f, a3 = 0.f;
    #pragma unroll 4
    for (int j = 0; j < NS; ++j) {
      float4 at = *(const float4*)&attnT[j * SA + i0];
      float hv = hr_s[j * SH + L];
      a0 = fmaf(at.x, hv, a0); a1 = fmaf(at.y, hv, a1);
      a2 = fmaf(at.z, hv, a2); a3 = fmaf(at.w, hv, a3);
    }
    size_t o = (size_t)(b * NS + i0) * HD + hh * NF + L;
    hg[o] = a0; hg[o + HD] = a1; hg[o + 2 * HD] = a2; hg[o + 3 * HD] = a3;
    hgb[o] = __float2bfloat16(a0); hgb[o + HD] = __float2bfloat16(a1);
    hgb[o + 2 * HD] = __float2bfloat16(a2); hgb[o + 3 * HD] = __float2bfloat16(a3);
  }
}
__global__ void __launch_bounds__(256, 1) k_gat(const float* hl, const float* hr, const void* adj, const void* Wa,
                      float* hg, bf16* hgb, int l, const int* flag) {
  __shared__ float hl_s[NS * SH];
  __shared__ float hr_s[NS * SH];
  __shared__ float attnT[NS * SA];
  __shared__ float wa04_s[NF];
  if (*flag) gat_body<bf16>(hl, hr, (const bf16*)adj, (const bf16*)Wa, hg, hgb, l, hl_s, hr_s, attnT, wa04_s);
  else gat_body<float>(hl, hr, (const float*)adj, (const float*)Wa, hg, hgb, l, hl_s, hr_s, attnT, wa04_s);
}

// ---------- fused ge-mean + all output heads + value: grid B
template <typename T>
__device__ void heads3_body(const float* x,
                            const T* cardW, const T* cardb, const T* atW, const T* atb,
                            const T* srcW, const T* srcb, const T* tgtW, const T* tgtb,
                            const T* v1W, const T* v1b, const T* v2W, const T* v2b,
                            T* out, float* sge, float* sh1) {
  int b = blockIdx.x, t = threadIdx.x;
  float a = 0.f;
  for (int s = 0; s < NS; ++s) a += x[(size_t)(b * NS + s) * HD + t];
  sge[t] = a * (1.f / NS);
  __syncthreads();
  for (int c = t; c < 385; c += 256) {
    const T* W; int ld, cc;
    if (c < 110)      { W = cardW; ld = 110; cc = c; }
    else if (c < 113) { W = atW;   ld = 3;   cc = c - 110; }
    else if (c < 185) { W = srcW;  ld = 72;  cc = c - 113; }
    else if (c < 257) { W = tgtW;  ld = 72;  cc = c - 185; }
    else              { W = v1W;   ld = 128; cc = c - 257; }
    float o = 0.f;
    #pragma unroll 8
    for (int k = 0; k < HD; ++k) o += sge[k] * ldv(W, k * ld + cc);
    if (c < 110)      stv(out, b * 110 + cc, o + ldv(cardb, cc));
    else if (c < 113) stv(out, 7040 + b * 3 + cc, o + ldv(atb, cc));
    else if (c < 185) stv(out, 7232 + b * 72 + cc, o + ldv(srcb, cc));
    else if (c < 257) stv(out, 11840 + b * 72 + cc, o + ldv(tgtb, cc));
    else              sh1[cc] = fmaxf(o + ldv(v1b, cc), 0.f);
  }
  __syncthreads();
  if (t < 64) {
    float v = sh1[t] * ldv(v2W, t) + sh1[t + 64] * ldv(v2W, t + 64);
    #pragma unroll
    for (int o = 32; o > 0; o >>= 1) v += __shfl_xor(v, o);
    if (t == 0) stv(out, 16448 + b, tanhf(v + ldv(v2b, 0)));
  }
}
__global__ void __launch_bounds__(256) k_heads3(const float* x,
                        const void* cardW, const void* cardb, const void* atW, const void* atb,
                        const void* srcW, const void* srcb, const void* tgtW, const void* tgtb,
                        const void* v1W, const void* v1b, const void* v2W, const void* v2b,
                        void* out, const int* flag) {
  __shared__ float sge[HD];
  __shared__ float sh1[128];
  if (*flag) heads3_body<bf16>(x, (const bf16*)cardW, (const bf16*)cardb, (const bf16*)atW,
                               (const bf16*)atb, (const bf16*)srcW, (const bf16*)srcb,
                               (const bf16*)tgtW, (const bf16*)tgtb, (const bf16*)v1W,
                               (const bf16*)v1b, (const bf16*)v2W, (const bf16*)v2b,
                               (bf16*)out, sge, sh1);
  else heads3_body<float>(x, (const float*)cardW, (const float*)cardb, (const float*)atW,
                          (const float*)atb, (const float*)srcW, (const float*)srcb,
                          (const float*)tgtW, (const float*)tgtb, (const float*)v1W,
                          (const float*)v1b, (const float*)v2W, (const float*)v2b,
                          (float*)out, sge, sh1);
}

extern "C" void kernel_launch(void* const* d_in, const int* in_sizes, int n_in,
                              void* d_out, int out_size, void* d_ws, size_t ws_size,
                              hipStream_t stream) {
  const void* spatial = d_in[0];
  const void* cardctx = d_in[1];
  const void* adj = d_in[2];
  const void* ctxW = d_in[3]; const void* ctxb = d_in[4];
  const void* lncs = d_in[5]; const void* lncb = d_in[6];
  const void* inW = d_in[7];  const void* inb = d_in[8];
  const void* lnps = d_in[9]; const void* lnpb = d_in[10];
  const void* cpW = d_in[11]; const void* cpb = d_in[12];
  const void* Wl = d_in[13];  const void* Wr = d_in[14]; const void* Wa = d_in[15];
  const void* opW = d_in[16]; const void* opb = d_in[17];
  const void* cardW = d_in[18]; const void* cardb = d_in[19];
  const void* atW = d_in[20];   const void* atb = d_in[21];
  const void* srcW = d_in[22];  const void* srcb = d_in[23];
  const void* tgtW = d_in[24];  const void* tgtb = d_in[25];
  const void* v1W = d_in[26];   const void* v1b = d_in[27];
  const void* v2W = d_in[28];   const void* v2b = d_in[29];

  int* flag = (int*)d_ws;
  float* base = (float*)((char*)d_ws + 256);
  float* g   = base;                  // B*HD
  float* c   = g + B * HD;            // NL*B*HD
  float* x   = c + NL * B * HD;       // B*NS*HD
  float* hf  = x + B * NS * HD;       // B*NS*HD (h f32, reused as hg f32)
  float* hl  = hf + B * NS * HD;      // B*NS*HD
  float* hr  = hl + B * NS * HD;      // B*NS*HD
  u16* breg  = (u16*)(hr + B * NS * HD);
  bf16* hb   = (bf16*)breg;           // B*NS*HD bf16
  bf16* hgb  = hb + B * NS * HD;      // B*NS*HD bf16
  u16* WT    = (u16*)(hgb + B * NS * HD); // 12*65536 bf16

  k_detect<<<1, 64, 0, stream>>>(adj, flag);
  k_wt<<<192, 256, 0, stream>>>(Wl, Wr, opW, WT, flag);
  k_ctx<<<B, HD, 0, stream>>>(cardctx, ctxW, ctxb, lncs, lncb, g, flag);
  k_inproj<<<B * NS, HD, 0, stream>>>(spatial, inW, inb, x, flag);
  k_cproja<<<NL * B * 4, 256, 0, stream>>>(g, cpW, cpb, c, flag);
  for (int l = 0; l < NL; ++l) {
    k_lnadd<<<B * NS, HD, 0, stream>>>(x, c + (size_t)l * B * HD, lnps, lnpb, hf, hb, l, flag);
    k_gemm_lr3<<<144, 256, 0, stream>>>(hb, hf, WT, Wl, Wr, hl, hr, l, flag);
    k_gat<<<B * NH, 256, 0, stream>>>(hl, hr, adj, Wa, hf, hgb, l, flag);
    k_gemm_op3<<<144, 256, 0, stream>>>(hgb, hf, WT, opW, opb, x, l, flag);
  }
  k_heads3<<<B, 256, 0, stream>>>(x, cardW, cardb, atW, atb, srcW, srcb, tgtW, tgtb,
                                  v1W, v1b, v2W, v2b, d_out, flag);
}